// Round 10
// baseline (246.198 us; speedup 1.0000x reference)
//
#include <hip/hip_runtime.h>

#define GRID_N 112
#define O_MAX 48
#define HW_N (GRID_N * GRID_N)   // 12544
#define NT 896                   // 14 waves: waves 0-6 -> batch 2g, 7-13 -> batch 2g+1
#define NBPB 2                   // batches per block, PARALLEL (disjoint wave-sets)

typedef _Float16 half8 __attribute__((ext_vector_type(8)));
typedef float    f32x4 __attribute__((ext_vector_type(4)));
typedef float    f32x2 __attribute__((ext_vector_type(2)));

// channel[b,h,w] = 0.5 + sum_k A[h,k]*B[w,k], masked by road_mask.
// A rows carry sign/scale: k<n -> -0.5*obj gauss, k==n -> +0.5*goal gauss, k>n -> 0.
//
// FAT-BLOCK A/B EXPERIMENT: per-wave instruction stream is IDENTICAL to the
// R5 fused kernel (best so far, 68 us); the only change is that each block
// carries TWO batches side-by-side on disjoint wave-sets -> workgroup count
// halves (2048 -> 1024) with zero serialization, zero LDS, zero barriers.
// Separates "per-WG dispatch/teardown tax" from "per-wave latency chain":
// the former predicts ~45-55 us; the latter predicts flat ~68 us.
__global__ __launch_bounds__(NT) void goalmap_kernel(
    const float* __restrict__ xL, const float* __restrict__ yL,
    const float* __restrict__ obj_list, const int* __restrict__ obj_num,
    const int* __restrict__ road_mask, float* __restrict__ out)
{
    constexpr float INV = 1.0f / (2.0f * 5.0f * 5.0f);  // SIGMA = 5.0

    const int tid  = threadIdx.x;
    const int lane = tid & 63;
    const int wid  = tid >> 6;                  // 0..13
    const int wb   = (wid >= 7) ? 1 : 0;        // which batch of the pair
    const int ws   = wid - wb * 7;              // 0..6: row strip within batch
    const int m    = lane & 15;
    const int quad = lane >> 4;

    const int b = blockIdx.x * NBPB + wb;       // grid 1024 x 2 batches

    const int n  = obj_num[b];                  // wave-uniform -> scalar
    const float xl = xL[b];
    const float yl = yL[b];
    const float* ob = obj_list + (size_t)b * (O_MAX * 2);
    const int*   rm = road_mask + (size_t)b * HW_N;
    float*       op = out       + (size_t)b * HW_N;

    // ---- (1) obj-coordinate gathers FIRST in the vmcnt FIFO. Guard is
    //      lane-static (k+32 < O_MAX), NOT n-dependent: issue never waits
    //      on the scalar loads; values past n are masked at use.
    f32x2 oc0[8], oc1[8];
    #pragma unroll
    for (int j = 0; j < 8; ++j) {
        int k = quad * 8 + j;                   // k in [0,32)
        oc0[j] = *(const f32x2*)&ob[k * 2];     // (y,x), always in-bounds
        f32x2 z = {0.f, 0.f};
        oc1[j] = (k + 32 < O_MAX) ? *(const f32x2*)&ob[(k + 32) * 2] : z;
    }
    __builtin_amdgcn_sched_barrier(0);          // pin issue order: coords < masks

    // ---- (2) mask loads SECOND (consumed last, at the stores)
    int mpf[7][4];
    const int h0 = ws * 16 + quad * 4;          // C/D row base for this lane
    #pragma unroll
    for (int i = 0; i < 7; ++i) {
        int base = h0 * GRID_N + i * 16 + m;
        #pragma unroll
        for (int r = 0; r < 4; ++r)
            mpf[i][r] = rm[base + r * GRID_N];
    }
    __builtin_amdgcn_sched_barrier(0);

    const int ksteps = (n >= 32) ? 2 : 1;       // wave-uniform

    // ---- (3) A-fragments in registers (signed/scaled): rows ws*16+m
    const float fh = (float)(ws * 16 + m);
    half8 a0, a1;
    #pragma unroll
    for (int j = 0; j < 8; ++j) {
        int k = quad * 8 + j;
        float val = 0.f;
        if (k <= n) {
            float cx = (k < n) ? oc0[j][1] : xl;
            float s  = (k < n) ? -0.5f  : 0.5f;
            float d  = fh - cx;
            val = s * __expf(-d * d * INV);
        }
        a0[j] = (_Float16)val;
    }
    if (ksteps == 2) {
        #pragma unroll
        for (int j = 0; j < 8; ++j) {
            int k = quad * 8 + j + 32;
            float val = 0.f;
            if (k <= n) {
                float cx = (k < n) ? oc1[j][1] : xl;
                float s  = (k < n) ? -0.5f  : 0.5f;
                float d  = fh - cx;
                val = s * __expf(-d * d * INV);
            }
            a1[j] = (_Float16)val;
        }
    }

    // ---- (4) tile sweep: B-fragments built privately per tile, MFMA,
    //      mask select, store. No sync with any other wave, ever.
    #pragma unroll
    for (int tw = 0; tw < 7; ++tw) {
        const float fw = (float)(tw * 16 + m);  // this lane's column
        half8 b0;
        #pragma unroll
        for (int j = 0; j < 8; ++j) {
            int k = quad * 8 + j;
            float val = 0.f;
            if (k <= n) {
                float cy = (k < n) ? oc0[j][0] : yl;
                float d  = fw - cy;
                val = __expf(-d * d * INV);
            }
            b0[j] = (_Float16)val;
        }
        f32x4 acc = {0.f, 0.f, 0.f, 0.f};
        acc = __builtin_amdgcn_mfma_f32_16x16x32_f16(a0, b0, acc, 0, 0, 0);
        if (ksteps == 2) {
            half8 b1;
            #pragma unroll
            for (int j = 0; j < 8; ++j) {
                int k = quad * 8 + j + 32;
                float val = 0.f;
                if (k <= n) {
                    float cy = (k < n) ? oc1[j][0] : yl;
                    float d  = fw - cy;
                    val = __expf(-d * d * INV);
                }
                b1[j] = (_Float16)val;
            }
            acc = __builtin_amdgcn_mfma_f32_16x16x32_f16(a1, b1, acc, 0, 0, 0);
        }

        const int w0 = tw * 16 + m;
        #pragma unroll
        for (int r = 0; r < 4; ++r) {
            float v = 0.5f + acc[r];
            v = (mpf[tw][r] == 0) ? 0.f : v;
            op[(h0 + r) * GRID_N + w0] = v;
        }
    }
}

extern "C" void kernel_launch(void* const* d_in, const int* in_sizes, int n_in,
                              void* d_out, int out_size, void* d_ws, size_t ws_size,
                              hipStream_t stream) {
    const float* xL        = (const float*)d_in[0];
    const float* yL        = (const float*)d_in[1];
    const float* obj_list  = (const float*)d_in[2];
    const int*   obj_num   = (const int*)d_in[3];
    const int*   road_mask = (const int*)d_in[4];
    float*       out       = (float*)d_out;
    const int B = in_sizes[0];  // 2048

    const int grid = B / NBPB;  // 1024 fat blocks, 2 parallel batches each
    goalmap_kernel<<<grid, NT, 0, stream>>>(xL, yL, obj_list, obj_num, road_mask, out);
}

// Round 11
// 204.302 us; speedup vs baseline: 1.2051x; 1.2051x over previous
//
#include <hip/hip_runtime.h>

#define GRID_N 112
#define O_MAX 48
#define HW_N (GRID_N * GRID_N)   // 12544
#define NT 448                   // 7 wave-private waves; wave w owns row strip w

typedef _Float16 half8 __attribute__((ext_vector_type(8)));
typedef float    f32x4 __attribute__((ext_vector_type(4)));
typedef float    f32x2 __attribute__((ext_vector_type(2)));
typedef int      i32x4 __attribute__((ext_vector_type(4)));

// channel[b,h,w] = 0.5 + sum_k ex[h,k]*ey[w,k], masked by road_mask.
// ex rows carry sign/scale: k<n -> -0.5*obj, k==n -> +0.5*goal, k>n -> 0.
//
// R5's wave-private dataflow (best: 68 us, zero LDS/barriers/conflicts) with
// SWAPPED MFMA operands (layout verified by R6's passing run): lane holds
// out[h=wid*16+m][w=tw*16+quad*4+r], r=0..3 -> direct f32x4 stores, and the
// road_mask loads as i32x4 from the SAME offsets. Both hot streams move from
// 28 dword to 7 dwordx4 instructions per wave (bytes identical, requests 4x
// wider, VMEM instrs 72 -> 30) with no LDS transpose -- R6's test minus its
// bank-conflict confound. If request width is irrelevant, this lands at R5's
// ~68 us, which is the best-known kernel anyway.
__global__ __launch_bounds__(NT) void goalmap_kernel(
    const float* __restrict__ xL, const float* __restrict__ yL,
    const float* __restrict__ obj_list, const int* __restrict__ obj_num,
    const int* __restrict__ road_mask, float* __restrict__ out)
{
    constexpr float INV = 1.0f / (2.0f * 5.0f * 5.0f);  // SIGMA = 5.0

    const int b    = blockIdx.x;
    const int tid  = threadIdx.x;
    const int lane = tid & 63;
    const int wid  = tid >> 6;                  // 0..6: row strip
    const int m    = lane & 15;
    const int quad = lane >> 4;

    const int n  = obj_num[b];                  // uniform -> scalar
    const float xl = xL[b];
    const float yl = yL[b];
    const float* ob = obj_list + (size_t)b * (O_MAX * 2);
    const int*   rm = road_mask + (size_t)b * HW_N;
    float*       op = out       + (size_t)b * HW_N;

    // ---- (1) obj-coordinate gathers FIRST in the vmcnt FIFO. Lane-static
    //      guard (k+32 < O_MAX), not n-dependent: issue waits on nothing;
    //      values past n are masked at use.
    f32x2 oc0[8], oc1[8];
    #pragma unroll
    for (int j = 0; j < 8; ++j) {
        int k = quad * 8 + j;                   // k in [0,32)
        oc0[j] = *(const f32x2*)&ob[k * 2];     // (y,x), always in-bounds
        f32x2 z = {0.f, 0.f};
        oc1[j] = (k + 32 < O_MAX) ? *(const f32x2*)&ob[(k + 32) * 2] : z;
    }
    __builtin_amdgcn_sched_barrier(0);          // pin issue order: coords < masks

    // ---- (2) mask loads: 7 x dwordx4/lane. Lane's 16 B covers exactly the
    //      4 output columns its MFMA accumulator will produce (same offsets
    //      as the stores) -- consumed last, at the stores.
    const int rowoff = (wid * 16 + m) * GRID_N; // output row h = wid*16+m
    i32x4 mk[7];
    #pragma unroll
    for (int tw = 0; tw < 7; ++tw)
        mk[tw] = *(const i32x4*)&rm[rowoff + tw * 16 + quad * 4];
    __builtin_amdgcn_sched_barrier(0);

    const int ksteps = (n >= 32) ? 2 : 1;       // wave-uniform

    // ---- (3) ex-fragment (SECOND mfma operand, carries sign/scale):
    //      rows h = wid*16+m, k-slice quad*8+j
    const float fh = (float)(wid * 16 + m);
    half8 a0, a1;
    #pragma unroll
    for (int j = 0; j < 8; ++j) {
        int k = quad * 8 + j;
        float val = 0.f;
        if (k <= n) {
            float cx = (k < n) ? oc0[j][1] : xl;
            float s  = (k < n) ? -0.5f  : 0.5f;
            float d  = fh - cx;
            val = s * __expf(-d * d * INV);
        }
        a0[j] = (_Float16)val;
    }
    if (ksteps == 2) {
        #pragma unroll
        for (int j = 0; j < 8; ++j) {
            int k = quad * 8 + j + 32;
            float val = 0.f;
            if (k <= n) {
                float cx = (k < n) ? oc1[j][1] : xl;
                float s  = (k < n) ? -0.5f  : 0.5f;
                float d  = fh - cx;
                val = s * __expf(-d * d * INV);
            }
            a1[j] = (_Float16)val;
        }
    }

    // ---- (4) tile sweep: ey-fragment (FIRST operand) at w = tw*16+m,
    //      swapped MFMA, f32x4 mask-select, f32x4 store. No LDS, no sync.
    #pragma unroll
    for (int tw = 0; tw < 7; ++tw) {
        const float fw = (float)(tw * 16 + m);  // this lane's ey position
        half8 e0;
        #pragma unroll
        for (int j = 0; j < 8; ++j) {
            int k = quad * 8 + j;
            float val = 0.f;
            if (k <= n) {
                float cy = (k < n) ? oc0[j][0] : yl;
                float d  = fw - cy;
                val = __expf(-d * d * INV);
            }
            e0[j] = (_Float16)val;
        }
        f32x4 acc = {0.f, 0.f, 0.f, 0.f};
        acc = __builtin_amdgcn_mfma_f32_16x16x32_f16(e0, a0, acc, 0, 0, 0);
        if (ksteps == 2) {
            half8 e1;
            #pragma unroll
            for (int j = 0; j < 8; ++j) {
                int k = quad * 8 + j + 32;
                float val = 0.f;
                if (k <= n) {
                    float cy = (k < n) ? oc1[j][0] : yl;
                    float d  = fw - cy;
                    val = __expf(-d * d * INV);
                }
                e1[j] = (_Float16)val;
            }
            acc = __builtin_amdgcn_mfma_f32_16x16x32_f16(e1, a1, acc, 0, 0, 0);
        }

        // lane holds out[h=wid*16+m][w = tw*16 + quad*4 + 0..3]
        i32x4 mm = mk[tw];
        f32x4 o;
        #pragma unroll
        for (int r = 0; r < 4; ++r) {
            float v = 0.5f + acc[r];
            o[r] = (mm[r] == 0) ? 0.f : v;
        }
        *(f32x4*)&op[rowoff + tw * 16 + quad * 4] = o;
    }
}

extern "C" void kernel_launch(void* const* d_in, const int* in_sizes, int n_in,
                              void* d_out, int out_size, void* d_ws, size_t ws_size,
                              hipStream_t stream) {
    const float* xL        = (const float*)d_in[0];
    const float* yL        = (const float*)d_in[1];
    const float* obj_list  = (const float*)d_in[2];
    const int*   obj_num   = (const int*)d_in[3];
    const int*   road_mask = (const int*)d_in[4];
    float*       out       = (float*)d_out;
    const int B = in_sizes[0];  // 2048

    goalmap_kernel<<<B, NT, 0, stream>>>(xL, yL, obj_list, obj_num, road_mask, out);
}

// Round 12
// 203.025 us; speedup vs baseline: 1.2126x; 1.0063x over previous
//
#include <hip/hip_runtime.h>

#define GRID_N 112
#define O_MAX 48
#define HW_N (GRID_N * GRID_N)   // 12544
#define NT 64                    // ONE wave per workgroup; grid 7 x 2048

typedef _Float16 half8 __attribute__((ext_vector_type(8)));
typedef float    f32x4 __attribute__((ext_vector_type(4)));
typedef float    f32x2 __attribute__((ext_vector_type(2)));
typedef int      i32x4 __attribute__((ext_vector_type(4)));

// channel[b,h,w] = 0.5 + sum_k ex[h,k]*ey[w,k], masked by road_mask.
// ex rows carry sign/scale: k<n -> -0.5*obj, k==n -> +0.5*goal, k>n -> 0.
//
// MINIMUM-WORKGROUP packaging experiment: per-wave instruction stream is
// byte-identical to R11 (best known, ties R5's 68 us), but each wave is its
// own workgroup (64 threads, 14336 WGs, 2D grid: x=strip, y=batch).
// Empirical law from 12 rounds: batches-in-flight/CU is pinned at ~1.4
// regardless of internals, and time is monotone-decreasing in WG count
// (512->86us, 1024->78, 2048->68). Wave-slot cap is now 32 blocks/CU; if the
// CP fills slots, batch residency can reach ~4.6/CU -> ~30-45 us.
__global__ __launch_bounds__(NT) void goalmap_kernel(
    const float* __restrict__ xL, const float* __restrict__ yL,
    const float* __restrict__ obj_list, const int* __restrict__ obj_num,
    const int* __restrict__ road_mask, float* __restrict__ out)
{
    constexpr float INV = 1.0f / (2.0f * 5.0f * 5.0f);  // SIGMA = 5.0

    const int b     = blockIdx.y;               // batch
    const int strip = blockIdx.x;               // 0..6: row strip (scalar!)
    const int lane  = threadIdx.x & 63;
    const int m     = lane & 15;
    const int quad  = lane >> 4;

    const int n  = obj_num[b];                  // uniform -> scalar
    const float xl = xL[b];
    const float yl = yL[b];
    const float* ob = obj_list + (size_t)b * (O_MAX * 2);
    const int*   rm = road_mask + (size_t)b * HW_N;
    float*       op = out       + (size_t)b * HW_N;

    // ---- (1) obj-coordinate gathers FIRST in the vmcnt FIFO. Lane-static
    //      guard (k+32 < O_MAX), not n-dependent: issue waits on nothing;
    //      values past n are masked at use.
    f32x2 oc0[8], oc1[8];
    #pragma unroll
    for (int j = 0; j < 8; ++j) {
        int k = quad * 8 + j;                   // k in [0,32)
        oc0[j] = *(const f32x2*)&ob[k * 2];     // (y,x), always in-bounds
        f32x2 z = {0.f, 0.f};
        oc1[j] = (k + 32 < O_MAX) ? *(const f32x2*)&ob[(k + 32) * 2] : z;
    }
    __builtin_amdgcn_sched_barrier(0);          // pin issue order: coords < masks

    // ---- (2) mask loads: 7 x dwordx4/lane, same offsets as the stores.
    const int rowoff = (strip * 16 + m) * GRID_N;  // output row h = strip*16+m
    i32x4 mk[7];
    #pragma unroll
    for (int tw = 0; tw < 7; ++tw)
        mk[tw] = *(const i32x4*)&rm[rowoff + tw * 16 + quad * 4];
    __builtin_amdgcn_sched_barrier(0);

    const int ksteps = (n >= 32) ? 2 : 1;       // wave-uniform

    // ---- (3) ex-fragment (SECOND mfma operand, carries sign/scale):
    //      rows h = strip*16+m, k-slice quad*8+j
    const float fh = (float)(strip * 16 + m);
    half8 a0, a1;
    #pragma unroll
    for (int j = 0; j < 8; ++j) {
        int k = quad * 8 + j;
        float val = 0.f;
        if (k <= n) {
            float cx = (k < n) ? oc0[j][1] : xl;
            float s  = (k < n) ? -0.5f  : 0.5f;
            float d  = fh - cx;
            val = s * __expf(-d * d * INV);
        }
        a0[j] = (_Float16)val;
    }
    if (ksteps == 2) {
        #pragma unroll
        for (int j = 0; j < 8; ++j) {
            int k = quad * 8 + j + 32;
            float val = 0.f;
            if (k <= n) {
                float cx = (k < n) ? oc1[j][1] : xl;
                float s  = (k < n) ? -0.5f  : 0.5f;
                float d  = fh - cx;
                val = s * __expf(-d * d * INV);
            }
            a1[j] = (_Float16)val;
        }
    }

    // ---- (4) tile sweep: ey-fragment (FIRST operand) at w = tw*16+m,
    //      swapped MFMA, f32x4 mask-select, f32x4 store. No LDS, no sync.
    #pragma unroll
    for (int tw = 0; tw < 7; ++tw) {
        const float fw = (float)(tw * 16 + m);  // this lane's ey position
        half8 e0;
        #pragma unroll
        for (int j = 0; j < 8; ++j) {
            int k = quad * 8 + j;
            float val = 0.f;
            if (k <= n) {
                float cy = (k < n) ? oc0[j][0] : yl;
                float d  = fw - cy;
                val = __expf(-d * d * INV);
            }
            e0[j] = (_Float16)val;
        }
        f32x4 acc = {0.f, 0.f, 0.f, 0.f};
        acc = __builtin_amdgcn_mfma_f32_16x16x32_f16(e0, a0, acc, 0, 0, 0);
        if (ksteps == 2) {
            half8 e1;
            #pragma unroll
            for (int j = 0; j < 8; ++j) {
                int k = quad * 8 + j + 32;
                float val = 0.f;
                if (k <= n) {
                    float cy = (k < n) ? oc1[j][0] : yl;
                    float d  = fw - cy;
                    val = __expf(-d * d * INV);
                }
                e1[j] = (_Float16)val;
            }
            acc = __builtin_amdgcn_mfma_f32_16x16x32_f16(e1, a1, acc, 0, 0, 0);
        }

        // lane holds out[h=strip*16+m][w = tw*16 + quad*4 + 0..3]
        i32x4 mm = mk[tw];
        f32x4 o;
        #pragma unroll
        for (int r = 0; r < 4; ++r) {
            float v = 0.5f + acc[r];
            o[r] = (mm[r] == 0) ? 0.f : v;
        }
        *(f32x4*)&op[rowoff + tw * 16 + quad * 4] = o;
    }
}

extern "C" void kernel_launch(void* const* d_in, const int* in_sizes, int n_in,
                              void* d_out, int out_size, void* d_ws, size_t ws_size,
                              hipStream_t stream) {
    const float* xL        = (const float*)d_in[0];
    const float* yL        = (const float*)d_in[1];
    const float* obj_list  = (const float*)d_in[2];
    const int*   obj_num   = (const int*)d_in[3];
    const int*   road_mask = (const int*)d_in[4];
    float*       out       = (float*)d_out;
    const int B = in_sizes[0];  // 2048

    dim3 grid(7, B);            // 14336 one-wave workgroups
    goalmap_kernel<<<grid, NT, 0, stream>>>(xL, yL, obj_list, obj_num, road_mask, out);
}